// Round 4
// baseline (350.352 us; speedup 1.0000x reference)
//
#include <hip/hip_runtime.h>
#include <cstdint>
#include <cstddef>

// Shapes (fixed by the reference problem)
#define D     1024
#define LSEQ  4096
#define BATCH 4
#define MROWS (BATCH * LSEQ)   // 16384 GEMM rows

typedef __attribute__((ext_vector_type(8))) __bf16 bf16x8;
typedef __attribute__((ext_vector_type(4))) float  f32x4;

__device__ __forceinline__ ushort f2bf(float f) {
  union { float f; uint32_t u; } v; v.f = f;
  uint32_t u = v.u;
  return (ushort)((u + 0x7fffu + ((u >> 16) & 1u)) >> 16);   // RNE
}
__device__ __forceinline__ float bf2f(ushort h) {
  union { uint32_t u; float f; } v; v.u = ((uint32_t)h) << 16; return v.f;
}
__device__ __forceinline__ float silu_f(float x) { return x / (1.f + expf(-x)); }

// async global->LDS, 16B per lane (dest = wave-uniform base + lane*16)
__device__ __forceinline__ void gl_lds16(const void* g, void* l) {
  __builtin_amdgcn_global_load_lds(
      (const __attribute__((address_space(1))) void*)g,
      (__attribute__((address_space(3))) void*)l, 16, 0, 0);
}

// ---------------------------------------------------------------------------
// Kernel A: Wp (f32, [D][D]) -> bf16
// ---------------------------------------------------------------------------
__global__ __launch_bounds__(256) void cvt_wp(const float* __restrict__ s,
                                              ushort* __restrict__ d) {
  const int i = (blockIdx.x * 256 + threadIdx.x) * 4;
  const float4 v = *reinterpret_cast<const float4*>(&s[i]);
  ushort4 o;
  o.x = f2bf(v.x); o.y = f2bf(v.y); o.z = f2bf(v.z); o.w = f2bf(v.w);
  *reinterpret_cast<ushort4*>(&d[i]) = o;
}

// ---------------------------------------------------------------------------
// Kernel B: h = bf16(silu(causal_dwconv_k3(u))); also u -> bf16 (GEMM A).
// 4 ch/thread, 8 rows/block -> grid (512,4)=2048 blocks (8 blocks/CU).
// ---------------------------------------------------------------------------
#define TL1 8
__global__ __launch_bounds__(256) void conv1_silu_cvt(
    const float* __restrict__ u, const float* __restrict__ w1,
    const float* __restrict__ b1, ushort* __restrict__ h,
    ushort* __restrict__ ubf) {
  const int c4 = threadIdx.x * 4;            // 256 threads x 4 ch = 1024
  const int b  = blockIdx.y;
  const int l0 = blockIdx.x * TL1;
  const size_t base = ((size_t)b * LSEQ) * D + c4;
  const float4 wa = *reinterpret_cast<const float4*>(&w1[c4]);
  const float4 wb = *reinterpret_cast<const float4*>(&w1[D + c4]);
  const float4 wc = *reinterpret_cast<const float4*>(&w1[2 * D + c4]);
  const float4 bi = *reinterpret_cast<const float4*>(&b1[c4]);
  float4 x0 = {0.f, 0.f, 0.f, 0.f}, x1 = {0.f, 0.f, 0.f, 0.f};
  if (l0 >= 2) x0 = *reinterpret_cast<const float4*>(&u[base + (size_t)(l0 - 2) * D]);
  if (l0 >= 1) x1 = *reinterpret_cast<const float4*>(&u[base + (size_t)(l0 - 1) * D]);
  #pragma unroll
  for (int l = l0; l < l0 + TL1; ++l) {
    const float4 x2 = *reinterpret_cast<const float4*>(&u[base + (size_t)l * D]);
    ushort4 ho, uo;
    ho.x = f2bf(silu_f(fmaf(x0.x, wa.x, fmaf(x1.x, wb.x, fmaf(x2.x, wc.x, bi.x)))));
    ho.y = f2bf(silu_f(fmaf(x0.y, wa.y, fmaf(x1.y, wb.y, fmaf(x2.y, wc.y, bi.y)))));
    ho.z = f2bf(silu_f(fmaf(x0.z, wa.z, fmaf(x1.z, wb.z, fmaf(x2.z, wc.z, bi.z)))));
    ho.w = f2bf(silu_f(fmaf(x0.w, wa.w, fmaf(x1.w, wb.w, fmaf(x2.w, wc.w, bi.w)))));
    uo.x = f2bf(x2.x); uo.y = f2bf(x2.y); uo.z = f2bf(x2.z); uo.w = f2bf(x2.w);
    *reinterpret_cast<ushort4*>(&h[base + (size_t)l * D])   = ho;
    *reinterpret_cast<ushort4*>(&ubf[base + (size_t)l * D]) = uo;
    x0 = x1; x1 = x2;
  }
}

// ---------------------------------------------------------------------------
// Kernel C: proj = silu(u @ Wp^T + bp) — bf16 MFMA, gl_lds staging, BK=64.
// grid (N-tiles=8, M-tiles=128): XCD = blockIdx%8 = N-panel -> B panel
// (256 KB) stays resident in that XCD's private L2.
// ---------------------------------------------------------------------------
#define BM 128
#define BN 128
#define BK 64
__global__ __launch_bounds__(256) void gemm_bias_silu(
    const ushort* __restrict__ A, const ushort* __restrict__ B,
    const float* __restrict__ bp, float* __restrict__ out) {
  __shared__ __align__(16) ushort lsA[BM][BK];   // 16 KiB
  __shared__ __align__(16) ushort lsB[BN][BK];   // 16 KiB
  const int tid  = threadIdx.x;
  const int wave = tid >> 6, lane = tid & 63;
  const int m0 = blockIdx.y * BM;
  const int n0 = blockIdx.x * BN;
  const int wr = (wave >> 1) * 64;
  const int wc = (wave & 1) * 64;
  const int fr = lane & 15;
  const int fk = (lane >> 4) * 8;
  char* ldsA = (char*)&lsA[0][0];
  char* ldsB = (char*)&lsB[0][0];

  f32x4 acc[4][4];
  #pragma unroll
  for (int i = 0; i < 4; ++i)
    #pragma unroll
    for (int j = 0; j < 4; ++j) acc[i][j] = f32x4{0.f, 0.f, 0.f, 0.f};

  for (int k0 = 0; k0 < D; k0 += BK) {
    #pragma unroll
    for (int q = 0; q < 4; ++q) {
      const int o = (wave * 4 + q) * 1024 + lane * 16;   // byte offset in tile
      const int r = o >> 7, ce = (o & 127) >> 1;         // 128 B per row
      gl_lds16(&A[(size_t)(m0 + r) * D + k0 + ce], ldsA + o);
      gl_lds16(&B[(size_t)(n0 + r) * D + k0 + ce], ldsB + o);
    }
    __syncthreads();
    #pragma unroll
    for (int kk = 0; kk < 2; ++kk) {
      bf16x8 af[4], bfr[4];
      #pragma unroll
      for (int i = 0; i < 4; ++i)
        af[i] = *reinterpret_cast<const bf16x8*>(&lsA[wr + i * 16 + fr][kk * 32 + fk]);
      #pragma unroll
      for (int j = 0; j < 4; ++j)
        bfr[j] = *reinterpret_cast<const bf16x8*>(&lsB[wc + j * 16 + fr][kk * 32 + fk]);
      #pragma unroll
      for (int i = 0; i < 4; ++i)
        #pragma unroll
        for (int j = 0; j < 4; ++j)
          acc[i][j] = __builtin_amdgcn_mfma_f32_16x16x32_bf16(af[i], bfr[j],
                                                              acc[i][j], 0, 0, 0);
    }
    __syncthreads();
  }
  const int ccol  = lane & 15;
  const int rbase = (lane >> 4) * 4;
  #pragma unroll
  for (int i = 0; i < 4; ++i) {
    #pragma unroll
    for (int j = 0; j < 4; ++j) {
      const int gn  = n0 + wc + j * 16 + ccol;
      const float bv = bp[gn];
      #pragma unroll
      for (int r = 0; r < 4; ++r) {
        const int gm = m0 + wr + i * 16 + rbase + r;
        out[(size_t)gm * D + gn] = silu_f(acc[i][j][r] + bv);
      }
    }
  }
}

// ---------------------------------------------------------------------------
// Kernel D: out = (causal_dwconv_k128(h_bf16) + b2) * proj   (proj in d_out)
// Block = 64 ch x 128 rows, 4 waves. h tile [255][64] bf16 + w2 transposed
// [64][130] bf16 in LDS (49.3 KB -> 3 blocks/CU). Each thread: channel
// c = tid&63; two groups of 16 rows (wave q -> rows q*16+g*64). Per group:
// hh[31] rolling window + acc[16] + pj[16] (proj loads hoisted to group
// start, latency hidden under 2048 FMAs) -> ~90 VGPR, no spill.
// ---------------------------------------------------------------------------
#define C2CH   64
#define C2TL   128
#define C2ROWS 255
__global__ __launch_bounds__(256, 3) void conv2_mul(
    const ushort* __restrict__ h, const float* __restrict__ w2,
    const float* __restrict__ b2, float* __restrict__ out) {
  __shared__ __align__(16) ushort hsb[C2ROWS * C2CH];   // 32640 B
  __shared__ ushort wsb[C2CH * 130];                    // 16640 B
  const int tid = threadIdx.x;
  const int c0  = blockIdx.x * C2CH;
  const int L0  = blockIdx.y * C2TL;
  const int b   = blockIdx.z;
  const ushort* hb = h + ((size_t)b * LSEQ) * D;

  // stage h rows [L0-127, L0+127] (128 B/row): 16 B per lane, contiguous
  {
    char* hdst = (char*)hsb;
    #pragma unroll
    for (int pass = 0; pass < 8; ++pass) {
      const int idx = pass * 4096 + tid * 16;          // byte index
      if (idx < C2ROWS * 128) {
        const int r = idx >> 7;
        const int g = L0 - 127 + r;
        int4 v = {0, 0, 0, 0};
        if (g >= 0)
          v = *reinterpret_cast<const int4*>(
                  &hb[(size_t)g * D + c0 + ((idx & 127) >> 1)]);
        *reinterpret_cast<int4*>(hdst + idx) = v;
      }
    }
  }
  // stage w2 slice (f32 -> bf16), transposed [ch][tap], row stride 130
  {
    #pragma unroll
    for (int p = 0; p < 8; ++p) {
      const int idx = p * 256 + tid;
      const int t = idx >> 4, ch4 = (idx & 15) * 4;
      const float4 wv =
          *reinterpret_cast<const float4*>(&w2[(size_t)t * D + c0 + ch4]);
      wsb[(ch4 + 0) * 130 + t] = f2bf(wv.x);
      wsb[(ch4 + 1) * 130 + t] = f2bf(wv.y);
      wsb[(ch4 + 2) * 130 + t] = f2bf(wv.z);
      wsb[(ch4 + 3) * 130 + t] = f2bf(wv.w);
    }
  }
  __syncthreads();

  const int c = tid & 63;
  const int q = tid >> 6;
  const float bias = b2[c0 + c];
  float* ob = out + ((size_t)b * LSEQ) * D + c0 + c;
  const ushort* hcol = &hsb[c];
  const char*   wrow = (const char*)&wsb[c * 130];

  #pragma unroll 1
  for (int g2 = 0; g2 < 2; ++g2) {
    const int ls0 = q * 16 + g2 * 64;      // group's output-row base (local)
    // hoist proj loads: independent, hidden under the 2048 FMAs below
    float pj[16];
    #pragma unroll
    for (int r = 0; r < 16; ++r)
      pj[r] = ob[(size_t)(L0 + ls0 + r) * D];

    float acc[16];
    #pragma unroll
    for (int r = 0; r < 16; ++r) acc[r] = 0.f;
    float hh[31];
    #pragma unroll
    for (int qq = 0; qq < 31; ++qq)
      hh[qq] = bf2f(hcol[(size_t)(ls0 + qq) * C2CH]);

    #pragma unroll
    for (int tb = 0; tb < 8; ++tb) {
      #pragma unroll
      for (int i2 = 0; i2 < 8; ++i2) {     // 8 tap-pairs of 2
        const uint32_t wp = *reinterpret_cast<const uint32_t*>(
            wrow + (size_t)(tb * 16 + i2 * 2) * 2);
        union { uint32_t u; float f; } wl, wh;
        wl.u = wp << 16; wh.u = wp & 0xffff0000u;
        #pragma unroll
        for (int r = 0; r < 16; ++r) {
          acc[r] = fmaf(wl.f, hh[i2 * 2 + r], acc[r]);
          acc[r] = fmaf(wh.f, hh[i2 * 2 + 1 + r], acc[r]);
        }
      }
      if (tb < 7) {                        // slide window by 16 taps
        #pragma unroll
        for (int qq = 0; qq < 15; ++qq) hh[qq] = hh[qq + 16];
        #pragma unroll
        for (int qq = 15; qq < 31; ++qq)
          hh[qq] = bf2f(hcol[(size_t)(ls0 + 16 * (tb + 1) + qq) * C2CH]);
      }
    }
    #pragma unroll
    for (int r = 0; r < 16; ++r)
      ob[(size_t)(L0 + ls0 + r) * D] = (acc[r] + bias) * pj[r];
  }
}

// ---------------------------------------------------------------------------
// Workspace layout (~66 MiB):
//   h    : bf16 [4][4096][1024] @ 0         (32 MiB)
//   ubf  : bf16 [16384][1024]   @ 33554432  (32 MiB)
//   wpbf : bf16 [1024][1024]    @ 67108864  ( 2 MiB)
// proj lives in d_out (GEMM writes it; conv2_mul multiplies in place).
// ---------------------------------------------------------------------------
extern "C" void kernel_launch(void* const* d_in, const int* in_sizes, int n_in,
                              void* d_out, int out_size, void* d_ws,
                              size_t ws_size, hipStream_t stream) {
  const float* u  = (const float*)d_in[0];
  const float* w1 = (const float*)d_in[1];
  const float* b1 = (const float*)d_in[2];
  const float* w2 = (const float*)d_in[3];
  const float* b2 = (const float*)d_in[4];
  const float* Wp = (const float*)d_in[5];
  const float* bp = (const float*)d_in[6];
  float* out = (float*)d_out;

  char* ws = (char*)d_ws;
  ushort* h    = (ushort*)(ws);
  ushort* ubf  = (ushort*)(ws + (size_t)33554432);
  ushort* wpbf = (ushort*)(ws + (size_t)67108864);

  cvt_wp<<<dim3(D * D / 1024), 256, 0, stream>>>(Wp, wpbf);
  conv1_silu_cvt<<<dim3(LSEQ / TL1, BATCH), 256, 0, stream>>>(
      u, w1, b1, h, ubf);
  gemm_bias_silu<<<dim3(D / BN, MROWS / BM), 256, 0, stream>>>(
      ubf, wpbf, bp, out);
  conv2_mul<<<dim3(D / C2CH, LSEQ / C2TL, BATCH), 256, 0, stream>>>(
      h, w2, b2, out);
}

// Round 5
// 299.127 us; speedup vs baseline: 1.1712x; 1.1712x over previous
//
#include <hip/hip_runtime.h>
#include <cstdint>
#include <cstddef>

// Shapes (fixed by the reference problem)
#define D     1024
#define LSEQ  4096
#define BATCH 4
#define MROWS (BATCH * LSEQ)   // 16384 GEMM rows

typedef __attribute__((ext_vector_type(8))) __bf16 bf16x8;
typedef __attribute__((ext_vector_type(4))) float  f32x4;

__device__ __forceinline__ ushort f2bf(float f) {
  union { float f; uint32_t u; } v; v.f = f;
  uint32_t u = v.u;
  return (ushort)((u + 0x7fffu + ((u >> 16) & 1u)) >> 16);   // RNE
}
__device__ __forceinline__ float bf2f(ushort h) {
  union { uint32_t u; float f; } v; v.u = ((uint32_t)h) << 16; return v.f;
}
__device__ __forceinline__ float silu_f(float x) { return x / (1.f + expf(-x)); }

// async global->LDS, 16B per lane (dest = wave-uniform base + lane*16)
__device__ __forceinline__ void gl_lds16(const void* g, void* l) {
  __builtin_amdgcn_global_load_lds(
      (const __attribute__((address_space(1))) void*)g,
      (__attribute__((address_space(3))) void*)l, 16, 0, 0);
}

// ---------------------------------------------------------------------------
// Kernel A: Wp (f32, [D][D]) -> bf16
// ---------------------------------------------------------------------------
__global__ __launch_bounds__(256) void cvt_wp(const float* __restrict__ s,
                                              ushort* __restrict__ d) {
  const int i = (blockIdx.x * 256 + threadIdx.x) * 4;
  const float4 v = *reinterpret_cast<const float4*>(&s[i]);
  ushort4 o;
  o.x = f2bf(v.x); o.y = f2bf(v.y); o.z = f2bf(v.z); o.w = f2bf(v.w);
  *reinterpret_cast<ushort4*>(&d[i]) = o;
}

// ---------------------------------------------------------------------------
// Kernel B: h = bf16(silu(causal_dwconv_k3(u))); also u -> bf16 (GEMM A).
// 4 ch/thread, 8 rows/block -> grid (512,4)=2048 blocks (8 blocks/CU).
// ---------------------------------------------------------------------------
#define TL1 8
__global__ __launch_bounds__(256) void conv1_silu_cvt(
    const float* __restrict__ u, const float* __restrict__ w1,
    const float* __restrict__ b1, ushort* __restrict__ h,
    ushort* __restrict__ ubf) {
  const int c4 = threadIdx.x * 4;            // 256 threads x 4 ch = 1024
  const int b  = blockIdx.y;
  const int l0 = blockIdx.x * TL1;
  const size_t base = ((size_t)b * LSEQ) * D + c4;
  const float4 wa = *reinterpret_cast<const float4*>(&w1[c4]);
  const float4 wb = *reinterpret_cast<const float4*>(&w1[D + c4]);
  const float4 wc = *reinterpret_cast<const float4*>(&w1[2 * D + c4]);
  const float4 bi = *reinterpret_cast<const float4*>(&b1[c4]);
  float4 x0 = {0.f, 0.f, 0.f, 0.f}, x1 = {0.f, 0.f, 0.f, 0.f};
  if (l0 >= 2) x0 = *reinterpret_cast<const float4*>(&u[base + (size_t)(l0 - 2) * D]);
  if (l0 >= 1) x1 = *reinterpret_cast<const float4*>(&u[base + (size_t)(l0 - 1) * D]);
  #pragma unroll
  for (int l = l0; l < l0 + TL1; ++l) {
    const float4 x2 = *reinterpret_cast<const float4*>(&u[base + (size_t)l * D]);
    ushort4 ho, uo;
    ho.x = f2bf(silu_f(fmaf(x0.x, wa.x, fmaf(x1.x, wb.x, fmaf(x2.x, wc.x, bi.x)))));
    ho.y = f2bf(silu_f(fmaf(x0.y, wa.y, fmaf(x1.y, wb.y, fmaf(x2.y, wc.y, bi.y)))));
    ho.z = f2bf(silu_f(fmaf(x0.z, wa.z, fmaf(x1.z, wb.z, fmaf(x2.z, wc.z, bi.z)))));
    ho.w = f2bf(silu_f(fmaf(x0.w, wa.w, fmaf(x1.w, wb.w, fmaf(x2.w, wc.w, bi.w)))));
    uo.x = f2bf(x2.x); uo.y = f2bf(x2.y); uo.z = f2bf(x2.z); uo.w = f2bf(x2.w);
    *reinterpret_cast<ushort4*>(&h[base + (size_t)l * D])   = ho;
    *reinterpret_cast<ushort4*>(&ubf[base + (size_t)l * D]) = uo;
    x0 = x1; x1 = x2;
  }
}

// ---------------------------------------------------------------------------
// Kernel C: proj = silu(u @ Wp^T + bp) — bf16 MFMA, gl_lds staging, BK=64.
// grid (N-tiles=8, M-tiles=128): XCD = blockIdx%8 = N-panel -> B panel
// (256 KB) stays resident in that XCD's private L2.
// ---------------------------------------------------------------------------
#define BM 128
#define BN 128
#define BK 64
__global__ __launch_bounds__(256) void gemm_bias_silu(
    const ushort* __restrict__ A, const ushort* __restrict__ B,
    const float* __restrict__ bp, float* __restrict__ out) {
  __shared__ __align__(16) ushort lsA[BM][BK];   // 16 KiB
  __shared__ __align__(16) ushort lsB[BN][BK];   // 16 KiB
  const int tid  = threadIdx.x;
  const int wave = tid >> 6, lane = tid & 63;
  const int m0 = blockIdx.y * BM;
  const int n0 = blockIdx.x * BN;
  const int wr = (wave >> 1) * 64;
  const int wc = (wave & 1) * 64;
  const int fr = lane & 15;
  const int fk = (lane >> 4) * 8;
  char* ldsA = (char*)&lsA[0][0];
  char* ldsB = (char*)&lsB[0][0];

  f32x4 acc[4][4];
  #pragma unroll
  for (int i = 0; i < 4; ++i)
    #pragma unroll
    for (int j = 0; j < 4; ++j) acc[i][j] = f32x4{0.f, 0.f, 0.f, 0.f};

  for (int k0 = 0; k0 < D; k0 += BK) {
    #pragma unroll
    for (int q = 0; q < 4; ++q) {
      const int o = (wave * 4 + q) * 1024 + lane * 16;   // byte offset in tile
      const int r = o >> 7, ce = (o & 127) >> 1;         // 128 B per row
      gl_lds16(&A[(size_t)(m0 + r) * D + k0 + ce], ldsA + o);
      gl_lds16(&B[(size_t)(n0 + r) * D + k0 + ce], ldsB + o);
    }
    __syncthreads();
    #pragma unroll
    for (int kk = 0; kk < 2; ++kk) {
      bf16x8 af[4], bfr[4];
      #pragma unroll
      for (int i = 0; i < 4; ++i)
        af[i] = *reinterpret_cast<const bf16x8*>(&lsA[wr + i * 16 + fr][kk * 32 + fk]);
      #pragma unroll
      for (int j = 0; j < 4; ++j)
        bfr[j] = *reinterpret_cast<const bf16x8*>(&lsB[wc + j * 16 + fr][kk * 32 + fk]);
      #pragma unroll
      for (int i = 0; i < 4; ++i)
        #pragma unroll
        for (int j = 0; j < 4; ++j)
          acc[i][j] = __builtin_amdgcn_mfma_f32_16x16x32_bf16(af[i], bfr[j],
                                                              acc[i][j], 0, 0, 0);
    }
    __syncthreads();
  }
  const int ccol  = lane & 15;
  const int rbase = (lane >> 4) * 4;
  #pragma unroll
  for (int i = 0; i < 4; ++i) {
    #pragma unroll
    for (int j = 0; j < 4; ++j) {
      const int gn  = n0 + wc + j * 16 + ccol;
      const float bv = bp[gn];
      #pragma unroll
      for (int r = 0; r < 4; ++r) {
        const int gm = m0 + wr + i * 16 + rbase + r;
        out[(size_t)gm * D + gn] = silu_f(acc[i][j][r] + bv);
      }
    }
  }
}

// ---------------------------------------------------------------------------
// Kernel D: out = (causal_dwconv_k128(h_bf16) + b2) * proj   (proj in d_out)
// Block = 64 ch x 128 rows, 4 waves. h tile [255][64] bf16 + w2 transposed
// [64][130] bf16 in LDS (49.3 KB -> 3 blocks/CU via LDS; NO min-waves
// launch bound — (256,3) capped VGPRs at 84 and forced ~240 MB of scratch
// spill traffic in R3/R4). Thread: channel c = tid&63, two groups of 16
// rows; live set hh[31]+acc[16]+misc ≈ 90 VGPR -> no spill.
// ---------------------------------------------------------------------------
#define C2CH   64
#define C2TL   128
#define C2ROWS 255
__global__ __launch_bounds__(256) void conv2_mul(
    const ushort* __restrict__ h, const float* __restrict__ w2,
    const float* __restrict__ b2, float* __restrict__ out) {
  __shared__ __align__(16) ushort hsb[C2ROWS * C2CH];   // 32640 B
  __shared__ ushort wsb[C2CH * 130];                    // 16640 B
  const int tid = threadIdx.x;
  const int c0  = blockIdx.x * C2CH;
  const int L0  = blockIdx.y * C2TL;
  const int b   = blockIdx.z;
  const ushort* hb = h + ((size_t)b * LSEQ) * D;

  // stage h rows [L0-127, L0+127] (128 B/row): 16 B per lane, contiguous
  {
    char* hdst = (char*)hsb;
    #pragma unroll
    for (int pass = 0; pass < 8; ++pass) {
      const int idx = pass * 4096 + tid * 16;          // byte index
      if (idx < C2ROWS * 128) {
        const int r = idx >> 7;
        const int g = L0 - 127 + r;
        int4 v = {0, 0, 0, 0};
        if (g >= 0)
          v = *reinterpret_cast<const int4*>(
                  &hb[(size_t)g * D + c0 + ((idx & 127) >> 1)]);
        *reinterpret_cast<int4*>(hdst + idx) = v;
      }
    }
  }
  // stage w2 slice (f32 -> bf16), transposed [ch][tap], row stride 130
  {
    #pragma unroll
    for (int p = 0; p < 8; ++p) {
      const int idx = p * 256 + tid;
      const int t = idx >> 4, ch4 = (idx & 15) * 4;
      const float4 wv =
          *reinterpret_cast<const float4*>(&w2[(size_t)t * D + c0 + ch4]);
      wsb[(ch4 + 0) * 130 + t] = f2bf(wv.x);
      wsb[(ch4 + 1) * 130 + t] = f2bf(wv.y);
      wsb[(ch4 + 2) * 130 + t] = f2bf(wv.z);
      wsb[(ch4 + 3) * 130 + t] = f2bf(wv.w);
    }
  }
  __syncthreads();

  const int c = tid & 63;
  const int q = tid >> 6;
  const float bias = b2[c0 + c];
  float* ob = out + ((size_t)b * LSEQ) * D + c0 + c;
  const ushort* hcol = &hsb[c];
  const char*   wrow = (const char*)&wsb[c * 130];

  #pragma unroll 1
  for (int g2 = 0; g2 < 2; ++g2) {
    const int ls0 = q * 16 + g2 * 64;      // group's output-row base (local)
    float acc[16];
    #pragma unroll
    for (int r = 0; r < 16; ++r) acc[r] = 0.f;
    float hh[31];
    #pragma unroll
    for (int qq = 0; qq < 31; ++qq)
      hh[qq] = bf2f(hcol[(size_t)(ls0 + qq) * C2CH]);

    #pragma unroll
    for (int tb = 0; tb < 8; ++tb) {
      #pragma unroll
      for (int i2 = 0; i2 < 8; ++i2) {     // 8 tap-pairs of 2
        const uint32_t wp = *reinterpret_cast<const uint32_t*>(
            wrow + (size_t)(tb * 16 + i2 * 2) * 2);
        union { uint32_t u; float f; } wl, wh;
        wl.u = wp << 16; wh.u = wp & 0xffff0000u;
        #pragma unroll
        for (int r = 0; r < 16; ++r) {
          acc[r] = fmaf(wl.f, hh[i2 * 2 + r], acc[r]);
          acc[r] = fmaf(wh.f, hh[i2 * 2 + 1 + r], acc[r]);
        }
      }
      if (tb < 7) {                        // slide window by 16 taps
        #pragma unroll
        for (int qq = 0; qq < 15; ++qq) hh[qq] = hh[qq + 16];
        #pragma unroll
        for (int qq = 15; qq < 31; ++qq)
          hh[qq] = bf2f(hcol[(size_t)(ls0 + 16 * (tb + 1) + qq) * C2CH]);
      }
    }
    // proj read + final store (coalesced 256B per row across the wave)
    #pragma unroll
    for (int r = 0; r < 16; ++r) {
      const size_t p = (size_t)(L0 + ls0 + r) * D;
      const float pj = ob[p];
      ob[p] = (acc[r] + bias) * pj;
    }
  }
}

// ---------------------------------------------------------------------------
// Workspace layout (~66 MiB):
//   h    : bf16 [4][4096][1024] @ 0         (32 MiB)
//   ubf  : bf16 [16384][1024]   @ 33554432  (32 MiB)
//   wpbf : bf16 [1024][1024]    @ 67108864  ( 2 MiB)
// proj lives in d_out (GEMM writes it; conv2_mul multiplies in place).
// ---------------------------------------------------------------------------
extern "C" void kernel_launch(void* const* d_in, const int* in_sizes, int n_in,
                              void* d_out, int out_size, void* d_ws,
                              size_t ws_size, hipStream_t stream) {
  const float* u  = (const float*)d_in[0];
  const float* w1 = (const float*)d_in[1];
  const float* b1 = (const float*)d_in[2];
  const float* w2 = (const float*)d_in[3];
  const float* b2 = (const float*)d_in[4];
  const float* Wp = (const float*)d_in[5];
  const float* bp = (const float*)d_in[6];
  float* out = (float*)d_out;

  char* ws = (char*)d_ws;
  ushort* h    = (ushort*)(ws);
  ushort* ubf  = (ushort*)(ws + (size_t)33554432);
  ushort* wpbf = (ushort*)(ws + (size_t)67108864);

  cvt_wp<<<dim3(D * D / 1024), 256, 0, stream>>>(Wp, wpbf);
  conv1_silu_cvt<<<dim3(LSEQ / TL1, BATCH), 256, 0, stream>>>(
      u, w1, b1, h, ubf);
  gemm_bias_silu<<<dim3(D / BN, MROWS / BM), 256, 0, stream>>>(
      ubf, wpbf, bp, out);
  conv2_mul<<<dim3(D / C2CH, LSEQ / C2TL, BATCH), 256, 0, stream>>>(
      h, w2, b2, out);
}